// Round 5
// baseline (201.110 us; speedup 1.0000x reference)
//
#include <hip/hip_runtime.h>
#include <hip/hip_bf16.h>
#include <stdint.h>
#include <utility>

// ---------------------------------------------------------------------------
// E=64 H=64 PRE1=512 BNK=1024 S=256 P=16 B=4096. Attention branch dead
// (softmax over size-1 axis == 1). Decomposition (rel is rank-2):
//   Z1[s,i,j,k] = rx*MX[k] + ry*MY[k] + HH[16s+j][k];  Y1 = relu(Z1)
//   out = maxpool_j relu(bn2(Y1 @ Wp2))
// v15: Phase C reshaped. v14 evidence: conflicts -29% -> time 0%; wall is
//   per-step latency: 4 ds_reads/step x 8 lockstep waves -> ~450cyc queue
//   latency vs lead-1 (~150cyc). v15:
//   (1) wave = 2 rowtiles x 4 coltiles (acc[2][4]=128 AGPR): ds_reads/step
//       halve (LDS pipe 24.6k->12.3k cyc/block); B frags/step 2->4
//       (B L2 2MB/block; rg-pair waves share B addrs -> L1 absorbs ~half).
//   (2) A ring-of-4 (lead 2 steps), B ring-of-3 (lead 2 steps >= L2 lat);
//       fully static 64-step schedule (template-constant unroll, constexpr
//       ring indices), waits vmcnt(8) lgkmcnt(4) steady, exact boundary/
//       tail literals; a2c2 in epilogue (in-order vmcnt retire).
//   (3) ab_probe kernel (Phases A+B only, guarded no-op store) = free
//       rocprof ablation of the A+B floor (mm2 overwrites all of out).
//   Regs ~122 arch + 128 acc ~= 250 <= 256 (2 waves/SIMD).
//   LDS = Y1 128K + HH 16K = 144 KB, 1 WG/CU, 8 waves, no K-loop barriers.
// ---------------------------------------------------------------------------

typedef __bf16 bf16x8 __attribute__((ext_vector_type(8)));
typedef __bf16 bf16x2 __attribute__((ext_vector_type(2)));
typedef float  f32x4  __attribute__((ext_vector_type(4)));
typedef float  f32x2  __attribute__((ext_vector_type(2)));
typedef float  f32x16 __attribute__((ext_vector_type(16)));

// workspace layout (bytes)
#define BP2_OFF 0u          // packed Wp2, 32x32x16 B-frags: [kstep(32)][ct(32)][l(64)]*16B = 1 MB
#define BP1_OFF 1048576u    // packed W1b (Wp1 rows 64..127): [nt(32)][kb(2)][l]*16B = 64 KB
#define MX_OFF  1114112u    // 512 f32
#define MY_OFF  1116160u
#define CB_OFF  1118208u
#define SH_OFF  1120256u
#define A2_OFF  1122304u    // 1024 f32
#define C2_OFF  1126400u

// mm2 LDS layout (bytes)
#define Y1_LDS  0           // bf16 [128 r][512 k], row stride 1024 B, off = ((c16^(r&7))<<4)
#define HH_LDS  131072      // bf16 [16 j][512 k], row stride 1024 B
#define LDS_SZ  147456      // 144 KB

__device__ __forceinline__ unsigned short f2bf(float f) {
    union { float f; unsigned u; } c; c.f = f;
    unsigned u = c.u;
    return (unsigned short)((u + 0x7fffu + ((u >> 16) & 1u)) >> 16);
}
__device__ __forceinline__ float bfbits2f(unsigned hi) {
    union { unsigned u; float f; } c; c.u = hi; return c.f;
}
__device__ __forceinline__ unsigned pk_bf16(float a, float b) {
#if __has_builtin(__builtin_amdgcn_cvt_pk_bf16_f32)
    bf16x2 p = __builtin_amdgcn_cvt_pk_bf16_f32(a, b);
    union { bf16x2 v; unsigned u; } c; c.v = p; return c.u;
#else
    return (unsigned)f2bf(a) | ((unsigned)f2bf(b) << 16);
#endif
}
// Y1 address: row r (0..127), 16-byte chunk c16 (0..63).
__device__ __forceinline__ int y1off(int r, int c16) {
    return r * 1024 + ((c16 ^ (r & 7)) << 4);
}

// static_for: fold over integral_constants (C++17)
template<class F, int... Is>
__device__ __forceinline__ void sf_impl(F& f, std::integer_sequence<int, Is...>) {
    (f(std::integral_constant<int, Is>{}), ...);
}
template<int N, class F>
__device__ __forceinline__ void static_for(F&& f) {
    sf_impl(f, std::make_integer_sequence<int, N>{});
}

// ---------------------------------------------------------------------------
// prep_pack: blocks 0..255 pack Wp2 into 32x32x16 B-frag layout
// ([kstep][ct][l]); 256..271 pack W1b (16x16x32 layout for Phase A);
// 272..279 fold k-consts (64 k each, 4-way e-split + LDS reduce);
// 280..283 fold A2/C2. All global reads coalesced.
// 32x32x16 B-frag: lane l holds B[k=kstep*16+(l>>5)*8+j][n=ct*32+(l&31)].
// 16x16x32 B-frag: lane l holds B[k=kb*32+(l>>4)*8+j][n=nt*16+(l&15)].
// ---------------------------------------------------------------------------
__global__ __launch_bounds__(256) void prep_pack_kernel(
    const float* __restrict__ Wsp,  const float* __restrict__ bsp,
    const float* __restrict__ Wp1,  const float* __restrict__ bp1,
    const float* __restrict__ gp1,  const float* __restrict__ btp1,
    const float* __restrict__ mp1,  const float* __restrict__ vp1,
    const float* __restrict__ Wp2,  const float* __restrict__ bp2,
    const float* __restrict__ gp2,  const float* __restrict__ btp2,
    const float* __restrict__ mp2,  const float* __restrict__ vp2,
    unsigned char* __restrict__ ws)
{
    __shared__ float tile[32 * 65];
    __shared__ float part[3][4][64];
    const int blk = blockIdx.x, t = threadIdx.x;

    if (blk < 272) {
        const float* src; int ncols, kb, ng;
        if (blk < 256) { kb = blk >> 4; ng = blk & 15; src = Wp2; ncols = 1024; }
        else { int b2 = blk - 256; kb = b2 >> 3; ng = b2 & 7; src = Wp1 + 64 * 512; ncols = 512; }
        const int k0 = kb * 32, n0 = ng * 64;
        #pragma unroll
        for (int it = 0; it < 2; ++it) {
            int c = t + it * 256;
            int r = c >> 4, c4 = c & 15;
            float4 v = *(const float4*)(src + (k0 + r) * ncols + n0 + c4 * 4);
            tile[r * 65 + c4 * 4 + 0] = v.x;
            tile[r * 65 + c4 * 4 + 1] = v.y;
            tile[r * 65 + c4 * 4 + 2] = v.z;
            tile[r * 65 + c4 * 4 + 3] = v.w;
        }
        __syncthreads();
        if (blk < 256) {
            const int l = t & 63, ch = (t >> 6) & 1, kh = t >> 7;
            const int nl = ch * 32 + (l & 31);
            const int kl = kh * 16 + ((l >> 5) & 1) * 8;
            uint4 o;
            o.x = pk_bf16(tile[(kl + 0) * 65 + nl], tile[(kl + 1) * 65 + nl]);
            o.y = pk_bf16(tile[(kl + 2) * 65 + nl], tile[(kl + 3) * 65 + nl]);
            o.z = pk_bf16(tile[(kl + 4) * 65 + nl], tile[(kl + 5) * 65 + nl]);
            o.w = pk_bf16(tile[(kl + 6) * 65 + nl], tile[(kl + 7) * 65 + nl]);
            const int kstep = kb * 2 + kh, ct = ng * 2 + ch;
            ((uint4*)(ws + BP2_OFF))[(kstep * 32 + ct) * 64 + l] = o;
        } else {
            int ntl = t >> 6, l = t & 63;
            int nl = ntl * 16 + (l & 15), kl = (l >> 4) * 8;
            uint4 o;
            o.x = pk_bf16(tile[(kl + 0) * 65 + nl], tile[(kl + 1) * 65 + nl]);
            o.y = pk_bf16(tile[(kl + 2) * 65 + nl], tile[(kl + 3) * 65 + nl]);
            o.z = pk_bf16(tile[(kl + 4) * 65 + nl], tile[(kl + 5) * 65 + nl]);
            o.w = pk_bf16(tile[(kl + 6) * 65 + nl], tile[(kl + 7) * 65 + nl]);
            ((uint4*)(ws + BP1_OFF))[((ng * 4 + ntl) * 2 + kb) * 64 + l] = o;
        }
    } else if (blk < 280) {
        const int kk = t & 63, eq = t >> 6;
        const int k = (blk - 272) * 64 + kk;
        float mx = 0.f, my = 0.f, cb = 0.f;
        #pragma unroll
        for (int e2 = 0; e2 < 16; ++e2) {
            int e = eq * 16 + e2;
            float wv = Wp1[e * 512 + k];
            mx = fmaf(Wsp[e],      wv, mx);
            my = fmaf(Wsp[64 + e], wv, my);
            cb = fmaf(bsp[e],      wv, cb);
        }
        part[0][eq][kk] = mx; part[1][eq][kk] = my; part[2][eq][kk] = cb;
        __syncthreads();
        if (t < 64) {
            const int k2 = (blk - 272) * 64 + t;
            float mxs = part[0][0][t] + part[0][1][t] + part[0][2][t] + part[0][3][t];
            float mys = part[1][0][t] + part[1][1][t] + part[1][2][t] + part[1][3][t];
            float cbs = part[2][0][t] + part[2][1][t] + part[2][2][t] + part[2][3][t];
            float a1 = gp1[k2] * rsqrtf(vp1[k2] + 1e-5f);
            ((float*)(ws + MX_OFF))[k2] = 0.05f * a1 * mxs;
            ((float*)(ws + MY_OFF))[k2] = 0.05f * a1 * mys;
            ((float*)(ws + CB_OFF))[k2] = 0.05f * a1 * cbs + (bp1[k2] - mp1[k2]) * a1 + btp1[k2];
            ((float*)(ws + SH_OFF))[k2] = 0.05f * a1;
        }
    } else {
        int n = (blk - 280) * 256 + t;
        float a = gp2[n] * rsqrtf(vp2[n] + 1e-5f);
        ((float*)(ws + A2_OFF))[n] = a;
        ((float*)(ws + C2_OFF))[n] = btp2[n] + (bp2[n] - mp2[n]) * a;
    }
}

// ---------------------------------------------------------------------------
// Phases A+B (shared by mm2 and ab_probe). Includes both barriers.
// ---------------------------------------------------------------------------
__device__ __forceinline__ void phaseAB(
    unsigned char* smem,
    const float* __restrict__ hst, const float* __restrict__ epos,
    const unsigned char* __restrict__ ws, int s, int ih, int tid)
{
    const int w    = tid >> 6;
    const int l    = tid & 63;
    const int quad = l >> 4;
    const int jl   = l & 15;

    // ---- Phase A: HH via MFMA (16x16x32) ----
    {
        union { unsigned u[4]; bf16x8 v; } afh[2];
        #pragma unroll
        for (int kb = 0; kb < 2; ++kb) {
            const float4* hp = (const float4*)(hst + (s * 16 + jl) * 64 + kb * 32 + quad * 8);
            float4 v0 = hp[0], v1 = hp[1];
            afh[kb].u[0] = pk_bf16(v0.x, v0.y);
            afh[kb].u[1] = pk_bf16(v0.z, v0.w);
            afh[kb].u[2] = pk_bf16(v1.x, v1.y);
            afh[kb].u[3] = pk_bf16(v1.z, v1.w);
        }
        const f32x4 fz = {0.f, 0.f, 0.f, 0.f};
        f32x4 acch[4] = {fz, fz, fz, fz};     // wave w -> k-cols w*64..+63
        #pragma unroll
        for (int kb = 0; kb < 2; ++kb) {
            #pragma unroll
            for (int ct = 0; ct < 4; ++ct) {
                bf16x8 bfr = *(const bf16x8*)(ws + BP1_OFF + ((((w * 4 + ct) * 2 + kb) * 64 + l) << 4));
                acch[ct] = __builtin_amdgcn_mfma_f32_16x16x32_bf16(afh[kb].v, bfr, acch[ct], 0, 0, 0);
            }
        }
        const float* SHg = (const float*)(ws + SH_OFF);
        const float* CBg = (const float*)(ws + CB_OFF);
        #pragma unroll
        for (int ct = 0; ct < 4; ++ct) {
            int col = (w * 4 + ct) * 16 + jl;        // k index
            float sh = SHg[col], cb = CBg[col];
            #pragma unroll
            for (int reg = 0; reg < 4; ++reg) {
                int j = quad * 4 + reg;
                float hv = fmaf(acch[ct][reg], sh, cb);
                *(unsigned short*)(smem + HH_LDS + j * 1024 + col * 2) = f2bf(hv);
            }
        }
    }
    __syncthreads();

    // ---- Phase B: construct Y1 (bf16, swizzled); chunk = kk*16+kc ----
    {
        const int i2 = tid >> 8;           // 0..1  (4 i each)
        const int j  = (tid >> 4) & 15;
        const int kc = tid & 15;
        float rx[4], ry[4];
        float pjx = epos[s * 32 + j * 2], pjy = epos[s * 32 + j * 2 + 1];
        #pragma unroll
        for (int ii = 0; ii < 4; ++ii) {
            int ig_ = ih * 8 + i2 * 4 + ii;
            rx[ii] = pjx - epos[s * 32 + ig_ * 2];
            ry[ii] = pjy - epos[s * 32 + ig_ * 2 + 1];
        }
        const f32x2 zero2 = {0.f, 0.f};
        #pragma unroll
        for (int kk = 0; kk < 4; ++kk) {
            int c16 = kk * 16 + kc;
            int k = c16 * 8;
            uint4 hh8 = *(const uint4*)(smem + HH_LDS + j * 1024 + k * 2);
            f32x4 mx0 = *(const f32x4*)(ws + MX_OFF + k * 4);
            f32x4 mx1 = *(const f32x4*)(ws + MX_OFF + k * 4 + 16);
            f32x4 my0 = *(const f32x4*)(ws + MY_OFF + k * 4);
            f32x4 my1 = *(const f32x4*)(ws + MY_OFF + k * 4 + 16);
            f32x2 mxp[4] = { {mx0[0],mx0[1]}, {mx0[2],mx0[3]}, {mx1[0],mx1[1]}, {mx1[2],mx1[3]} };
            f32x2 myp[4] = { {my0[0],my0[1]}, {my0[2],my0[3]}, {my1[0],my1[1]}, {my1[2],my1[3]} };
            f32x2 hhp[4];
            hhp[0][0] = bfbits2f(hh8.x << 16); hhp[0][1] = bfbits2f(hh8.x & 0xffff0000u);
            hhp[1][0] = bfbits2f(hh8.y << 16); hhp[1][1] = bfbits2f(hh8.y & 0xffff0000u);
            hhp[2][0] = bfbits2f(hh8.z << 16); hhp[2][1] = bfbits2f(hh8.z & 0xffff0000u);
            hhp[3][0] = bfbits2f(hh8.w << 16); hhp[3][1] = bfbits2f(hh8.w & 0xffff0000u);
            #pragma unroll
            for (int ii = 0; ii < 4; ++ii) {
                f32x2 rx2 = { rx[ii], rx[ii] };
                f32x2 ry2 = { ry[ii], ry[ii] };
                uint4 o;
                unsigned uu[4];
                #pragma unroll
                for (int p = 0; p < 4; ++p) {
                    f32x2 tt = __builtin_elementwise_fma(ry2, myp[p], hhp[p]);
                    tt = __builtin_elementwise_fma(rx2, mxp[p], tt);
                    tt = __builtin_elementwise_max(tt, zero2);
                    uu[p] = pk_bf16(tt[0], tt[1]);
                }
                o.x = uu[0]; o.y = uu[1]; o.z = uu[2]; o.w = uu[3];
                int r = (i2 * 4 + ii) * 16 + j;
                *(uint4*)(smem + Y1_LDS + y1off(r, c16)) = o;
            }
        }
    }
    __syncthreads();
}

// ---------------------------------------------------------------------------
// ab_probe: Phases A+B only. Guarded (effectively never-taken, harmless if
// taken: mm2 rewrites every out element) store keeps all work live. Its
// rocprof dispatch time = the A+B floor.
// ---------------------------------------------------------------------------
__global__ __launch_bounds__(512, 2) void ab_probe_kernel(
    const float* __restrict__ hst, const float* __restrict__ epos,
    const unsigned char* __restrict__ ws, float* __restrict__ out)
{
    __shared__ __align__(16) unsigned char smem[LDS_SZ];
    const int s = blockIdx.x >> 1, ih = blockIdx.x & 1, tid = threadIdx.x;
    phaseAB(smem, hst, epos, ws, s, ih, tid);
    if (((const unsigned int*)smem)[(tid * 67) & 32767] == 0xDEADBEEFu)
        out[tid] = -1.0f;
}

// ---------------------------------------------------------------------------
// mm2 v15: WG = (scene s, i-half ih). 512 thr = 8 waves = 2 rowgroups x
// 4 colgroups. Phase C: 2rt x 4ct per wave, 2 passes (16 coltiles each),
// static 64-step schedule, A ring-4 lead-2, B ring-3 lead-2.
// ---------------------------------------------------------------------------
__global__ __launch_bounds__(512, 2) void mm2_kernel(
    const float* __restrict__ hst,
    const float* __restrict__ epos,
    const unsigned char* __restrict__ ws,
    float* __restrict__ out)
{
    __shared__ __align__(16) unsigned char smem[LDS_SZ];

    const int s   = blockIdx.x >> 1;     // 256 scenes
    const int ih  = blockIdx.x & 1;      // i-half
    const int tid = threadIdx.x;

    phaseAB(smem, hst, epos, ws, s, ih, tid);

    // ---- Phase C ----
    const int w = tid >> 6, l = tid & 63;
    const int lane31 = l & 31;           // A-frag m, C col
    const int hi = l >> 5;               // k-half; C row group
    const int sr = lane31 & 7;
    const int rg = w >> 2;               // rowgroup: rowtiles rg*2, rg*2+1
    const int cg = w & 3;                // colgroup: 4 coltiles per pass
    const float* A2 = (const float*)(ws + A2_OFF);
    const float* C2 = (const float*)(ws + C2_OFF);

    // A addr(rr, k) = ((av + (k>>2)*128) ^ ((k&3)<<5)) + rr*32768
    const int av = Y1_LDS + (rg * 64 + lane31) * 1024 + ((hi ^ sr) << 4);
    // B addr(pass, k, c) = bp + pass*16384 + k*32768 + c*1024
    const unsigned char* bp = ws + BP2_OFF + ((cg * 4) << 10) + (l << 4);

    const f32x16 fz16 = {0.f,0.f,0.f,0.f,0.f,0.f,0.f,0.f,
                         0.f,0.f,0.f,0.f,0.f,0.f,0.f,0.f};
    f32x16 acc[2][4];
    bf16x8 ar[4][2];   // A ring-of-4 (lead 2), slot = k&3
    bf16x8 br[3][4];   // B ring-of-3 (lead 2), slot = G%3

    #pragma unroll
    for (int rr = 0; rr < 2; ++rr)
        #pragma unroll
        for (int c = 0; c < 4; ++c) acc[rr][c] = fz16;

    // epilogue: bn2 + relu, maxpool over j, store fp32. 8 loads + 8 stores.
    // C/D 32x32: col = lane&31, row = (reg&3)+8*(reg>>2)+4*hi.
    auto epilogue = [&](int pass) {
        #pragma unroll
        for (int c = 0; c < 4; ++c) {
            const int col = (pass * 16 + cg * 4 + c) * 32 + lane31;
            const float a2 = A2[col], c2 = C2[col];
            #pragma unroll
            for (int rr = 0; rr < 2; ++rr) {
                float mv[2];
                #pragma unroll
                for (int hg = 0; hg < 2; ++hg) {
                    float v0 = fmaxf(fmaf(acc[rr][c][hg * 8 + 0], a2, c2), 0.f);
                    float v1 = fmaxf(fmaf(acc[rr][c][hg * 8 + 1], a2, c2), 0.f);
                    float v2 = fmaxf(fmaf(acc[rr][c][hg * 8 + 2], a2, c2), 0.f);
                    float v3 = fmaxf(fmaf(acc[rr][c][hg * 8 + 3], a2, c2), 0.f);
                    float v4 = fmaxf(fmaf(acc[rr][c][hg * 8 + 4], a2, c2), 0.f);
                    float v5 = fmaxf(fmaf(acc[rr][c][hg * 8 + 5], a2, c2), 0.f);
                    float v6 = fmaxf(fmaf(acc[rr][c][hg * 8 + 6], a2, c2), 0.f);
                    float v7 = fmaxf(fmaf(acc[rr][c][hg * 8 + 7], a2, c2), 0.f);
                    float m = fmaxf(fmaxf(fmaxf(v0, v1), fmaxf(v2, v3)),
                                    fmaxf(fmaxf(v4, v5), fmaxf(v6, v7)));
                    mv[hg] = fmaxf(m, __shfl_xor(m, 32, 64));
                }
                const int iloc = (rg * 2 + rr) * 2 + hi;
                const float vout = hi ? mv[1] : mv[0];
                const int orow = s * 16 + ih * 8 + iloc;
                __builtin_nontemporal_store(vout, &out[orow * 1024 + col]);
            }
        }
    };

    // one step of the global 64-step schedule (G = pass*32 + k)
    auto stepG = [&](auto Gc) {
        constexpr int G  = decltype(Gc)::value;
        constexpr int GN = G + 2;                   // issue distance 2
        if constexpr (GN <= 63) {
            constexpr int pn = GN >> 5, kn = GN & 31;
            constexpr int bs = GN % 3, as = GN & 3;
            const unsigned char* b = bp + (pn * 16384 + kn * 32768);
            #pragma unroll
            for (int c = 0; c < 4; ++c)
                br[bs][c] = __builtin_nontemporal_load((const bf16x8*)(b + c * 1024));
            constexpr int add = (kn >> 2) * 128;
            constexpr int xr  = (kn & 3) << 5;
            ar[as][0] = *(const bf16x8*)(smem + ((av + add) ^ xr));
            ar[as][1] = *(const bf16x8*)(smem + (((av + add) ^ xr) + 32768));
        }
        if constexpr (G == 32)      asm volatile("s_waitcnt vmcnt(12) lgkmcnt(4)" ::: "memory");
        else if constexpr (G == 33) asm volatile("s_waitcnt vmcnt(16) lgkmcnt(4)" ::: "memory");
        else if constexpr (G == 62) asm volatile("s_waitcnt vmcnt(4) lgkmcnt(2)" ::: "memory");
        else if constexpr (G == 63) asm volatile("s_waitcnt vmcnt(0) lgkmcnt(0)" ::: "memory");
        else                        asm volatile("s_waitcnt vmcnt(8) lgkmcnt(4)" ::: "memory");
        __builtin_amdgcn_sched_barrier(0);
        constexpr int as2 = G & 3, bs2 = G % 3;
        #pragma unroll
        for (int c = 0; c < 4; ++c)
            #pragma unroll
            for (int rr = 0; rr < 2; ++rr)
                acc[rr][c] = __builtin_amdgcn_mfma_f32_32x32x16_bf16(
                    ar[as2][rr], br[bs2][c], acc[rr][c], 0, 0, 0);
    };

    // prologue: B(0),B(1) (8 loads); A(0),A(1) (4 ds_reads)
    #pragma unroll
    for (int g = 0; g < 2; ++g)
        #pragma unroll
        for (int c = 0; c < 4; ++c)
            br[g][c] = __builtin_nontemporal_load((const bf16x8*)(bp + g * 32768 + c * 1024));
    ar[0][0] = *(const bf16x8*)(smem + av);
    ar[0][1] = *(const bf16x8*)(smem + av + 32768);
    ar[1][0] = *(const bf16x8*)(smem + (av ^ 32));
    ar[1][1] = *(const bf16x8*)(smem + ((av ^ 32) + 32768));

    static_for<32>(stepG);                          // G = 0..31 (pass 0)
    __builtin_amdgcn_sched_barrier(0);
    epilogue(0);
    #pragma unroll
    for (int rr = 0; rr < 2; ++rr)
        #pragma unroll
        for (int c = 0; c < 4; ++c) acc[rr][c] = fz16;
    __builtin_amdgcn_sched_barrier(0);
    static_for<32>([&](auto kc) {                   // G = 32..63 (pass 1)
        stepG(std::integral_constant<int, decltype(kc)::value + 32>{});
    });
    __builtin_amdgcn_sched_barrier(0);
    epilogue(1);
}

extern "C" void kernel_launch(void* const* d_in, const int* in_sizes, int n_in,
                              void* d_out, int out_size, void* d_ws, size_t ws_size,
                              hipStream_t stream) {
    const float* hst  = (const float*)d_in[0];
    const float* epos = (const float*)d_in[1];
    const float* Wsp  = (const float*)d_in[4];
    const float* bsp  = (const float*)d_in[5];
    const float* Wp1  = (const float*)d_in[20];
    const float* bp1  = (const float*)d_in[21];
    const float* gp1  = (const float*)d_in[22];
    const float* btp1 = (const float*)d_in[23];
    const float* mp1  = (const float*)d_in[24];
    const float* vp1  = (const float*)d_in[25];
    const float* Wp2  = (const float*)d_in[26];
    const float* bp2  = (const float*)d_in[27];
    const float* gp2  = (const float*)d_in[28];
    const float* btp2 = (const float*)d_in[29];
    const float* mp2  = (const float*)d_in[30];
    const float* vp2  = (const float*)d_in[31];
    unsigned char* ws = (unsigned char*)d_ws;
    float* out = (float*)d_out;

    // 256 (Wp2 pack) + 16 (W1b pack) + 8 (k-consts) + 4 (A2/C2) = 284 blocks
    prep_pack_kernel<<<284, 256, 0, stream>>>(Wsp, bsp, Wp1, bp1, gp1, btp1, mp1, vp1,
                                              Wp2, bp2, gp2, btp2, mp2, vp2, ws);
    // A+B floor probe (separate rocprof dispatch; out is rewritten by mm2)
    ab_probe_kernel<<<512, 512, 0, stream>>>(hst, epos, ws, out);
    // 256 scenes x 2 i-halves, 512 threads (8 waves)
    mm2_kernel<<<512, 512, 0, stream>>>(hst, epos, ws, out);
}

// Round 6
// 196.153 us; speedup vs baseline: 1.0253x; 1.0253x over previous
//
#include <hip/hip_runtime.h>
#include <hip/hip_bf16.h>
#include <stdint.h>
#include <utility>

// ---------------------------------------------------------------------------
// E=64 H=64 PRE1=512 BNK=1024 S=256 P=16 B=4096. Attention branch dead
// (softmax over size-1 axis == 1). Decomposition (rel is rank-2):
//   Z1[s,i,j,k] = rx*MX[k] + ry*MY[k] + HH[16s+j][k];  Y1 = relu(Z1)
//   out = maxpool_j relu(bn2(Y1 @ Wp2))
// v16: v14 shape (wave = 4rt x 2ct; A 2MB / B 1MB per block -- proven
//   optimal corner: v15's A1/B2 mix was +19%), with DEEPER A pipelining.
//   v14 evidence: conflicts -29% -> 0%; v15: LDS-halving irrelevant,
//   B-doubling hurts. Remaining wall = per-step latency; v14's A lead was
//   only 1 step (lgkmcnt(4)) vs ~several-hundred-cycle effective LDS
//   latency (8 waves x 4 ds_read_b128 bursts + queueing). v16:
//   - A ring-of-3, lead-2: wait lgkmcnt(8) (A(G+1),A(G+2) in flight).
//   - B ring-of-3, lead-2: wait vmcnt(4).
//   - One continuous 64-step static schedule (constexpr ring slots),
//     mid-epilogue at G==31 counted into the boundary waits: after B(32)
//     there are exactly 16 vm ops (B33:2 + a2c2:4 + stores:8 + B34:2)
//     -> vmcnt(16) at G=32/33; tail vmcnt(2)/lgkmcnt(4) then 0/0.
//   Regs: ar 48 + br 24 + acc 128 + misc ~ 124+128 <= 256 (2 waves/SIMD).
//   LDS = Y1 128K + HH 16K = 144 KB, 1 WG/CU, 8 waves, no K-loop barriers.
// ---------------------------------------------------------------------------

typedef __bf16 bf16x8 __attribute__((ext_vector_type(8)));
typedef __bf16 bf16x2 __attribute__((ext_vector_type(2)));
typedef float  f32x4  __attribute__((ext_vector_type(4)));
typedef float  f32x2  __attribute__((ext_vector_type(2)));
typedef float  f32x16 __attribute__((ext_vector_type(16)));

// workspace layout (bytes)
#define BP2_OFF 0u          // packed Wp2, 32x32x16 B-frags: [kstep(32)][ct(32)][l(64)]*16B = 1 MB
#define BP1_OFF 1048576u    // packed W1b (Wp1 rows 64..127): [nt(32)][kb(2)][l]*16B = 64 KB
#define MX_OFF  1114112u    // 512 f32
#define MY_OFF  1116160u
#define CB_OFF  1118208u
#define SH_OFF  1120256u
#define A2_OFF  1122304u    // 1024 f32
#define C2_OFF  1126400u

// mm2 LDS layout (bytes)
#define Y1_LDS  0           // bf16 [128 r][512 k], row stride 1024 B, off = ((c16^(r&7))<<4)
#define HH_LDS  131072      // bf16 [16 j][512 k], row stride 1024 B
#define LDS_SZ  147456      // 144 KB

__device__ __forceinline__ unsigned short f2bf(float f) {
    union { float f; unsigned u; } c; c.f = f;
    unsigned u = c.u;
    return (unsigned short)((u + 0x7fffu + ((u >> 16) & 1u)) >> 16);
}
__device__ __forceinline__ float bfbits2f(unsigned hi) {
    union { unsigned u; float f; } c; c.u = hi; return c.f;
}
__device__ __forceinline__ unsigned pk_bf16(float a, float b) {
#if __has_builtin(__builtin_amdgcn_cvt_pk_bf16_f32)
    bf16x2 p = __builtin_amdgcn_cvt_pk_bf16_f32(a, b);
    union { bf16x2 v; unsigned u; } c; c.v = p; return c.u;
#else
    return (unsigned)f2bf(a) | ((unsigned)f2bf(b) << 16);
#endif
}
// Y1 address: row r (0..127), 16-byte chunk c16 (0..63).
__device__ __forceinline__ int y1off(int r, int c16) {
    return r * 1024 + ((c16 ^ (r & 7)) << 4);
}

// static_for: fold over integral_constants (C++17)
template<class F, int... Is>
__device__ __forceinline__ void sf_impl(F& f, std::integer_sequence<int, Is...>) {
    (f(std::integral_constant<int, Is>{}), ...);
}
template<int N, class F>
__device__ __forceinline__ void static_for(F&& f) {
    sf_impl(f, std::make_integer_sequence<int, N>{});
}

// ---------------------------------------------------------------------------
// prep_pack: blocks 0..255 pack Wp2 into 32x32x16 B-frag layout
// ([kstep][ct][l]); 256..271 pack W1b (16x16x32 layout for Phase A);
// 272..279 fold k-consts (64 k each, 4-way e-split + LDS reduce);
// 280..283 fold A2/C2. All global reads coalesced.
// 32x32x16 B-frag: lane l holds B[k=kstep*16+(l>>5)*8+j][n=ct*32+(l&31)].
// 16x16x32 B-frag: lane l holds B[k=kb*32+(l>>4)*8+j][n=nt*16+(l&15)].
// ---------------------------------------------------------------------------
__global__ __launch_bounds__(256) void prep_pack_kernel(
    const float* __restrict__ Wsp,  const float* __restrict__ bsp,
    const float* __restrict__ Wp1,  const float* __restrict__ bp1,
    const float* __restrict__ gp1,  const float* __restrict__ btp1,
    const float* __restrict__ mp1,  const float* __restrict__ vp1,
    const float* __restrict__ Wp2,  const float* __restrict__ bp2,
    const float* __restrict__ gp2,  const float* __restrict__ btp2,
    const float* __restrict__ mp2,  const float* __restrict__ vp2,
    unsigned char* __restrict__ ws)
{
    __shared__ float tile[32 * 65];
    __shared__ float part[3][4][64];
    const int blk = blockIdx.x, t = threadIdx.x;

    if (blk < 272) {
        const float* src; int ncols, kb, ng;
        if (blk < 256) { kb = blk >> 4; ng = blk & 15; src = Wp2; ncols = 1024; }
        else { int b2 = blk - 256; kb = b2 >> 3; ng = b2 & 7; src = Wp1 + 64 * 512; ncols = 512; }
        const int k0 = kb * 32, n0 = ng * 64;
        #pragma unroll
        for (int it = 0; it < 2; ++it) {
            int c = t + it * 256;
            int r = c >> 4, c4 = c & 15;
            float4 v = *(const float4*)(src + (k0 + r) * ncols + n0 + c4 * 4);
            tile[r * 65 + c4 * 4 + 0] = v.x;
            tile[r * 65 + c4 * 4 + 1] = v.y;
            tile[r * 65 + c4 * 4 + 2] = v.z;
            tile[r * 65 + c4 * 4 + 3] = v.w;
        }
        __syncthreads();
        if (blk < 256) {
            const int l = t & 63, ch = (t >> 6) & 1, kh = t >> 7;
            const int nl = ch * 32 + (l & 31);
            const int kl = kh * 16 + ((l >> 5) & 1) * 8;
            uint4 o;
            o.x = pk_bf16(tile[(kl + 0) * 65 + nl], tile[(kl + 1) * 65 + nl]);
            o.y = pk_bf16(tile[(kl + 2) * 65 + nl], tile[(kl + 3) * 65 + nl]);
            o.z = pk_bf16(tile[(kl + 4) * 65 + nl], tile[(kl + 5) * 65 + nl]);
            o.w = pk_bf16(tile[(kl + 6) * 65 + nl], tile[(kl + 7) * 65 + nl]);
            const int kstep = kb * 2 + kh, ct = ng * 2 + ch;
            ((uint4*)(ws + BP2_OFF))[(kstep * 32 + ct) * 64 + l] = o;
        } else {
            int ntl = t >> 6, l = t & 63;
            int nl = ntl * 16 + (l & 15), kl = (l >> 4) * 8;
            uint4 o;
            o.x = pk_bf16(tile[(kl + 0) * 65 + nl], tile[(kl + 1) * 65 + nl]);
            o.y = pk_bf16(tile[(kl + 2) * 65 + nl], tile[(kl + 3) * 65 + nl]);
            o.z = pk_bf16(tile[(kl + 4) * 65 + nl], tile[(kl + 5) * 65 + nl]);
            o.w = pk_bf16(tile[(kl + 6) * 65 + nl], tile[(kl + 7) * 65 + nl]);
            ((uint4*)(ws + BP1_OFF))[((ng * 4 + ntl) * 2 + kb) * 64 + l] = o;
        }
    } else if (blk < 280) {
        const int kk = t & 63, eq = t >> 6;
        const int k = (blk - 272) * 64 + kk;
        float mx = 0.f, my = 0.f, cb = 0.f;
        #pragma unroll
        for (int e2 = 0; e2 < 16; ++e2) {
            int e = eq * 16 + e2;
            float wv = Wp1[e * 512 + k];
            mx = fmaf(Wsp[e],      wv, mx);
            my = fmaf(Wsp[64 + e], wv, my);
            cb = fmaf(bsp[e],      wv, cb);
        }
        part[0][eq][kk] = mx; part[1][eq][kk] = my; part[2][eq][kk] = cb;
        __syncthreads();
        if (t < 64) {
            const int k2 = (blk - 272) * 64 + t;
            float mxs = part[0][0][t] + part[0][1][t] + part[0][2][t] + part[0][3][t];
            float mys = part[1][0][t] + part[1][1][t] + part[1][2][t] + part[1][3][t];
            float cbs = part[2][0][t] + part[2][1][t] + part[2][2][t] + part[2][3][t];
            float a1 = gp1[k2] * rsqrtf(vp1[k2] + 1e-5f);
            ((float*)(ws + MX_OFF))[k2] = 0.05f * a1 * mxs;
            ((float*)(ws + MY_OFF))[k2] = 0.05f * a1 * mys;
            ((float*)(ws + CB_OFF))[k2] = 0.05f * a1 * cbs + (bp1[k2] - mp1[k2]) * a1 + btp1[k2];
            ((float*)(ws + SH_OFF))[k2] = 0.05f * a1;
        }
    } else {
        int n = (blk - 280) * 256 + t;
        float a = gp2[n] * rsqrtf(vp2[n] + 1e-5f);
        ((float*)(ws + A2_OFF))[n] = a;
        ((float*)(ws + C2_OFF))[n] = btp2[n] + (bp2[n] - mp2[n]) * a;
    }
}

// ---------------------------------------------------------------------------
// Phases A+B (both barriers included).
// ---------------------------------------------------------------------------
__device__ __forceinline__ void phaseAB(
    unsigned char* smem,
    const float* __restrict__ hst, const float* __restrict__ epos,
    const unsigned char* __restrict__ ws, int s, int ih, int tid)
{
    const int w    = tid >> 6;
    const int l    = tid & 63;
    const int quad = l >> 4;
    const int jl   = l & 15;

    // ---- Phase A: HH via MFMA (16x16x32) ----
    {
        union { unsigned u[4]; bf16x8 v; } afh[2];
        #pragma unroll
        for (int kb = 0; kb < 2; ++kb) {
            const float4* hp = (const float4*)(hst + (s * 16 + jl) * 64 + kb * 32 + quad * 8);
            float4 v0 = hp[0], v1 = hp[1];
            afh[kb].u[0] = pk_bf16(v0.x, v0.y);
            afh[kb].u[1] = pk_bf16(v0.z, v0.w);
            afh[kb].u[2] = pk_bf16(v1.x, v1.y);
            afh[kb].u[3] = pk_bf16(v1.z, v1.w);
        }
        const f32x4 fz = {0.f, 0.f, 0.f, 0.f};
        f32x4 acch[4] = {fz, fz, fz, fz};     // wave w -> k-cols w*64..+63
        #pragma unroll
        for (int kb = 0; kb < 2; ++kb) {
            #pragma unroll
            for (int ct = 0; ct < 4; ++ct) {
                bf16x8 bfr = *(const bf16x8*)(ws + BP1_OFF + ((((w * 4 + ct) * 2 + kb) * 64 + l) << 4));
                acch[ct] = __builtin_amdgcn_mfma_f32_16x16x32_bf16(afh[kb].v, bfr, acch[ct], 0, 0, 0);
            }
        }
        const float* SHg = (const float*)(ws + SH_OFF);
        const float* CBg = (const float*)(ws + CB_OFF);
        #pragma unroll
        for (int ct = 0; ct < 4; ++ct) {
            int col = (w * 4 + ct) * 16 + jl;        // k index
            float sh = SHg[col], cb = CBg[col];
            #pragma unroll
            for (int reg = 0; reg < 4; ++reg) {
                int j = quad * 4 + reg;
                float hv = fmaf(acch[ct][reg], sh, cb);
                *(unsigned short*)(smem + HH_LDS + j * 1024 + col * 2) = f2bf(hv);
            }
        }
    }
    __syncthreads();

    // ---- Phase B: construct Y1 (bf16, swizzled); chunk = kk*16+kc ----
    {
        const int i2 = tid >> 8;           // 0..1  (4 i each)
        const int j  = (tid >> 4) & 15;
        const int kc = tid & 15;
        float rx[4], ry[4];
        float pjx = epos[s * 32 + j * 2], pjy = epos[s * 32 + j * 2 + 1];
        #pragma unroll
        for (int ii = 0; ii < 4; ++ii) {
            int ig_ = ih * 8 + i2 * 4 + ii;
            rx[ii] = pjx - epos[s * 32 + ig_ * 2];
            ry[ii] = pjy - epos[s * 32 + ig_ * 2 + 1];
        }
        const f32x2 zero2 = {0.f, 0.f};
        #pragma unroll
        for (int kk = 0; kk < 4; ++kk) {
            int c16 = kk * 16 + kc;
            int k = c16 * 8;
            uint4 hh8 = *(const uint4*)(smem + HH_LDS + j * 1024 + k * 2);
            f32x4 mx0 = *(const f32x4*)(ws + MX_OFF + k * 4);
            f32x4 mx1 = *(const f32x4*)(ws + MX_OFF + k * 4 + 16);
            f32x4 my0 = *(const f32x4*)(ws + MY_OFF + k * 4);
            f32x4 my1 = *(const f32x4*)(ws + MY_OFF + k * 4 + 16);
            f32x2 mxp[4] = { {mx0[0],mx0[1]}, {mx0[2],mx0[3]}, {mx1[0],mx1[1]}, {mx1[2],mx1[3]} };
            f32x2 myp[4] = { {my0[0],my0[1]}, {my0[2],my0[3]}, {my1[0],my1[1]}, {my1[2],my1[3]} };
            f32x2 hhp[4];
            hhp[0][0] = bfbits2f(hh8.x << 16); hhp[0][1] = bfbits2f(hh8.x & 0xffff0000u);
            hhp[1][0] = bfbits2f(hh8.y << 16); hhp[1][1] = bfbits2f(hh8.y & 0xffff0000u);
            hhp[2][0] = bfbits2f(hh8.z << 16); hhp[2][1] = bfbits2f(hh8.z & 0xffff0000u);
            hhp[3][0] = bfbits2f(hh8.w << 16); hhp[3][1] = bfbits2f(hh8.w & 0xffff0000u);
            #pragma unroll
            for (int ii = 0; ii < 4; ++ii) {
                f32x2 rx2 = { rx[ii], rx[ii] };
                f32x2 ry2 = { ry[ii], ry[ii] };
                uint4 o;
                unsigned uu[4];
                #pragma unroll
                for (int p = 0; p < 4; ++p) {
                    f32x2 tt = __builtin_elementwise_fma(ry2, myp[p], hhp[p]);
                    tt = __builtin_elementwise_fma(rx2, mxp[p], tt);
                    tt = __builtin_elementwise_max(tt, zero2);
                    uu[p] = pk_bf16(tt[0], tt[1]);
                }
                o.x = uu[0]; o.y = uu[1]; o.z = uu[2]; o.w = uu[3];
                int r = (i2 * 4 + ii) * 16 + j;
                *(uint4*)(smem + Y1_LDS + y1off(r, c16)) = o;
            }
        }
    }
    __syncthreads();
}

// ---------------------------------------------------------------------------
// mm2 v16: WG = (scene s, i-half ih). 512 thr = 8 waves, wave = 4rt x 2ct
// (coltiles w*4..w*4+3 over two chunks). Continuous 64-step schedule,
// A ring-3 lead-2 (lgkmcnt(8)), B ring-3 lead-2 (vmcnt(4)).
// ---------------------------------------------------------------------------
__global__ __launch_bounds__(512, 2) void mm2_kernel(
    const float* __restrict__ hst,
    const float* __restrict__ epos,
    const unsigned char* __restrict__ ws,
    float* __restrict__ out)
{
    __shared__ __align__(16) unsigned char smem[LDS_SZ];

    const int s   = blockIdx.x >> 1;     // 256 scenes
    const int ih  = blockIdx.x & 1;      // i-half
    const int tid = threadIdx.x;

    phaseAB(smem, hst, epos, ws, s, ih, tid);

    // ---- Phase C ----
    const int w = tid >> 6, l = tid & 63;
    const int lane31 = l & 31;           // A-frag m, C col
    const int hi = l >> 5;               // k-half; C row group
    const int sr = lane31 & 7;
    const float* A2 = (const float*)(ws + A2_OFF);
    const float* C2 = (const float*)(ws + C2_OFF);

    // A addr(rt, k) = (av[rt] + (k>>2)*128) ^ ((k&3)<<5)
    int av[4];
    #pragma unroll
    for (int rt = 0; rt < 4; ++rt)
        av[rt] = Y1_LDS + (rt * 32 + lane31) * 1024 + ((hi ^ sr) << 4);

    const int ctb0 = w * 4;              // this wave's 4 coltiles
    const unsigned char* bp = ws + BP2_OFF + (ctb0 << 10) + (l << 4);
    // B addr(G) = bp + (G>>5)*2048 + (G&31)*32768 + c*1024

    const f32x16 fz16 = {0.f,0.f,0.f,0.f,0.f,0.f,0.f,0.f,
                         0.f,0.f,0.f,0.f,0.f,0.f,0.f,0.f};
    f32x16 acc[4][2];
    bf16x8 ar[3][4];       // A ring-of-3, slot = G%3
    bf16x8 br[3][2];       // B ring-of-3, slot = G%3
    float a2v[2][2], c2v[2][2];

    // epilogue: bn2 + relu, maxpool over j, store fp32. 8 stores.
    // C/D 32x32: col = lane&31, row = (reg&3)+8*(reg>>2)+4*hi.
    auto epilogue = [&](int chunk) {
        #pragma unroll
        for (int c = 0; c < 2; ++c) {
            const int col = (ctb0 + chunk * 2 + c) * 32 + lane31;
            const float a2 = a2v[chunk][c], c2 = c2v[chunk][c];
            #pragma unroll
            for (int rt = 0; rt < 4; ++rt) {
                float mv[2];
                #pragma unroll
                for (int hg = 0; hg < 2; ++hg) {
                    float v0 = fmaxf(fmaf(acc[rt][c][hg * 8 + 0], a2, c2), 0.f);
                    float v1 = fmaxf(fmaf(acc[rt][c][hg * 8 + 1], a2, c2), 0.f);
                    float v2 = fmaxf(fmaf(acc[rt][c][hg * 8 + 2], a2, c2), 0.f);
                    float v3 = fmaxf(fmaf(acc[rt][c][hg * 8 + 3], a2, c2), 0.f);
                    float v4 = fmaxf(fmaf(acc[rt][c][hg * 8 + 4], a2, c2), 0.f);
                    float v5 = fmaxf(fmaf(acc[rt][c][hg * 8 + 5], a2, c2), 0.f);
                    float v6 = fmaxf(fmaf(acc[rt][c][hg * 8 + 6], a2, c2), 0.f);
                    float v7 = fmaxf(fmaf(acc[rt][c][hg * 8 + 7], a2, c2), 0.f);
                    float m = fmaxf(fmaxf(fmaxf(v0, v1), fmaxf(v2, v3)),
                                    fmaxf(fmaxf(v4, v5), fmaxf(v6, v7)));
                    mv[hg] = fmaxf(m, __shfl_xor(m, 32, 64));
                }
                const int iloc = rt * 2 + hi;      // hi=0 even i, hi=1 odd
                const float vout = hi ? mv[1] : mv[0];
                const int orow = s * 16 + ih * 8 + iloc;
                __builtin_nontemporal_store(vout, &out[orow * 1024 + col]);
            }
        }
    };

    // issue loads for global step GN (B: 2 loads; A: 4 ds_reads)
    auto issueG = [&](auto Gc) {
        constexpr int GN = decltype(Gc)::value;
        constexpr int ch = GN >> 5, kn = GN & 31, sl = GN % 3;
        constexpr int boff = ch * 2048 + kn * 32768;
        br[sl][0] = __builtin_nontemporal_load((const bf16x8*)(bp + boff));
        br[sl][1] = __builtin_nontemporal_load((const bf16x8*)(bp + boff + 1024));
        constexpr int add = (kn >> 2) * 128;
        constexpr int xr  = (kn & 3) << 5;
        #pragma unroll
        for (int rt = 0; rt < 4; ++rt)
            ar[sl][rt] = *(const bf16x8*)(smem + ((av[rt] + add) ^ xr));
    };

    auto stepG = [&](auto Gc) {
        constexpr int G = decltype(Gc)::value;
        if constexpr (G + 2 <= 63)
            issueG(std::integral_constant<int, G + 2>{});
        // waits: steady = B lead-2 (vmcnt 4), A lead-2 (lgkmcnt 8).
        // G=32/33: +12 epilogue vm ops (4 a2c2 loads + 8 stores) in flight.
        if constexpr (G == 32 || G == 33)
            asm volatile("s_waitcnt vmcnt(16) lgkmcnt(8)" ::: "memory");
        else if constexpr (G == 62)
            asm volatile("s_waitcnt vmcnt(2) lgkmcnt(4)" ::: "memory");
        else if constexpr (G == 63)
            asm volatile("s_waitcnt vmcnt(0) lgkmcnt(0)" ::: "memory");
        else
            asm volatile("s_waitcnt vmcnt(4) lgkmcnt(8)" ::: "memory");
        __builtin_amdgcn_sched_barrier(0);
        constexpr int sl = G % 3;
        #pragma unroll
        for (int c = 0; c < 2; ++c)
            #pragma unroll
            for (int rt = 0; rt < 4; ++rt)
                acc[rt][c] = __builtin_amdgcn_mfma_f32_32x32x16_bf16(
                    ar[sl][rt], br[sl][c], acc[rt][c], 0, 0, 0);
        if constexpr (G == 31) {
            // a2c2 chunk1 (4 vm loads, issued before the stores), then
            // epilogue chunk0 (8 stores), then acc reset.
            a2v[1][0] = A2[(ctb0 + 2) * 32 + lane31];
            a2v[1][1] = A2[(ctb0 + 3) * 32 + lane31];
            c2v[1][0] = C2[(ctb0 + 2) * 32 + lane31];
            c2v[1][1] = C2[(ctb0 + 3) * 32 + lane31];
            epilogue(0);
            #pragma unroll
            for (int rt = 0; rt < 4; ++rt) { acc[rt][0] = fz16; acc[rt][1] = fz16; }
        }
    };

    // prologue: a2c2 chunk0 (4 vm), B(0),B(1) (4 vm), A(0),A(1) (8 lgkm)
    a2v[0][0] = A2[ctb0 * 32 + lane31];
    a2v[0][1] = A2[(ctb0 + 1) * 32 + lane31];
    c2v[0][0] = C2[ctb0 * 32 + lane31];
    c2v[0][1] = C2[(ctb0 + 1) * 32 + lane31];
    #pragma unroll
    for (int rt = 0; rt < 4; ++rt) { acc[rt][0] = fz16; acc[rt][1] = fz16; }
    issueG(std::integral_constant<int, 0>{});
    issueG(std::integral_constant<int, 1>{});

    static_for<64>(stepG);
    __builtin_amdgcn_sched_barrier(0);
    epilogue(1);
}

extern "C" void kernel_launch(void* const* d_in, const int* in_sizes, int n_in,
                              void* d_out, int out_size, void* d_ws, size_t ws_size,
                              hipStream_t stream) {
    const float* hst  = (const float*)d_in[0];
    const float* epos = (const float*)d_in[1];
    const float* Wsp  = (const float*)d_in[4];
    const float* bsp  = (const float*)d_in[5];
    const float* Wp1  = (const float*)d_in[20];
    const float* bp1  = (const float*)d_in[21];
    const float* gp1  = (const float*)d_in[22];
    const float* btp1 = (const float*)d_in[23];
    const float* mp1  = (const float*)d_in[24];
    const float* vp1  = (const float*)d_in[25];
    const float* Wp2  = (const float*)d_in[26];
    const float* bp2  = (const float*)d_in[27];
    const float* gp2  = (const float*)d_in[28];
    const float* btp2 = (const float*)d_in[29];
    const float* mp2  = (const float*)d_in[30];
    const float* vp2  = (const float*)d_in[31];
    unsigned char* ws = (unsigned char*)d_ws;
    float* out = (float*)d_out;

    // 256 (Wp2 pack) + 16 (W1b pack) + 8 (k-consts) + 4 (A2/C2) = 284 blocks
    prep_pack_kernel<<<284, 256, 0, stream>>>(Wsp, bsp, Wp1, bp1, gp1, btp1, mp1, vp1,
                                              Wp2, bp2, gp2, btp2, mp2, vp2, ws);
    // 256 scenes x 2 i-halves, 512 threads (8 waves)
    mm2_kernel<<<512, 512, 0, stream>>>(hst, epos, ws, out);
}

// Round 7
// 186.768 us; speedup vs baseline: 1.0768x; 1.0502x over previous
//
#include <hip/hip_runtime.h>
#include <hip/hip_bf16.h>
#include <stdint.h>
#include <utility>

// ---------------------------------------------------------------------------
// E=64 H=64 PRE1=512 BNK=1024 S=256 P=16 B=4096. Attention branch dead
// (softmax over size-1 axis == 1). Decomposition (rel is rank-2):
//   Z1[s,i,j,k] = rx*MX[k] + ry*MY[k] + HH[16s+j][k];  Y1 = relu(Z1)
//   out = maxpool_j relu(bn2(Y1 @ Wp2))
// v17: v15 (wave = 2rt x 4ct, A ring-4 lead-2, B ring-3 lead-2, epilogues
//   OUTSIDE the unrolled folds -- the no-spill structure) with CACHED B
//   loads. v15's B loads were nontemporal -> L1 bypassed, but its two
//   rowgroups read IDENTICAL B addresses; nt forced 2 MB of L2-latency
//   traffic. Cached loads give ~50% L1 hits -> B effective cost back to
//   ~v14 level while LDS traffic stays halved (16 b128/step vs 32).
//   Also: corrected boundary waits (in-order vmcnt retire):
//     G=32/33: vmcnt(16) (epi 16 vm ops + B lead); G>=34: steady vmcnt(8)
//     covers B(G) exactly; tail vmcnt(4)/lgkm(2) then 0/0.
//   v16 lesson applied: epilogue inside the unroll = live-range bulge =
//   spill (FETCH 17MB/WRITE 50MB); epilogues here stay between folds.
//   Bank-conflict counters: wave64 b128 is inherently 8-lane/bank; m134's
//   12cyc/b128 includes it. Not a lever -- stop chasing.
//   Regs ~124 arch + 128 acc (v15-measured, no spill).
//   LDS = Y1 128K + HH 16K = 144 KB, 1 WG/CU, 8 waves, no K-loop barriers.
// ---------------------------------------------------------------------------

typedef __bf16 bf16x8 __attribute__((ext_vector_type(8)));
typedef __bf16 bf16x2 __attribute__((ext_vector_type(2)));
typedef float  f32x4  __attribute__((ext_vector_type(4)));
typedef float  f32x2  __attribute__((ext_vector_type(2)));
typedef float  f32x16 __attribute__((ext_vector_type(16)));

// workspace layout (bytes)
#define BP2_OFF 0u          // packed Wp2, 32x32x16 B-frags: [kstep(32)][ct(32)][l(64)]*16B = 1 MB
#define BP1_OFF 1048576u    // packed W1b (Wp1 rows 64..127): [nt(32)][kb(2)][l]*16B = 64 KB
#define MX_OFF  1114112u    // 512 f32
#define MY_OFF  1116160u
#define CB_OFF  1118208u
#define SH_OFF  1120256u
#define A2_OFF  1122304u    // 1024 f32
#define C2_OFF  1126400u

// mm2 LDS layout (bytes)
#define Y1_LDS  0           // bf16 [128 r][512 k], row stride 1024 B, off = ((c16^(r&7))<<4)
#define HH_LDS  131072      // bf16 [16 j][512 k], row stride 1024 B
#define LDS_SZ  147456      // 144 KB

__device__ __forceinline__ unsigned short f2bf(float f) {
    union { float f; unsigned u; } c; c.f = f;
    unsigned u = c.u;
    return (unsigned short)((u + 0x7fffu + ((u >> 16) & 1u)) >> 16);
}
__device__ __forceinline__ float bfbits2f(unsigned hi) {
    union { unsigned u; float f; } c; c.u = hi; return c.f;
}
__device__ __forceinline__ unsigned pk_bf16(float a, float b) {
#if __has_builtin(__builtin_amdgcn_cvt_pk_bf16_f32)
    bf16x2 p = __builtin_amdgcn_cvt_pk_bf16_f32(a, b);
    union { bf16x2 v; unsigned u; } c; c.v = p; return c.u;
#else
    return (unsigned)f2bf(a) | ((unsigned)f2bf(b) << 16);
#endif
}
// Y1 address: row r (0..127), 16-byte chunk c16 (0..63).
__device__ __forceinline__ int y1off(int r, int c16) {
    return r * 1024 + ((c16 ^ (r & 7)) << 4);
}

// static_for: fold over integral_constants (C++17)
template<class F, int... Is>
__device__ __forceinline__ void sf_impl(F& f, std::integer_sequence<int, Is...>) {
    (f(std::integral_constant<int, Is>{}), ...);
}
template<int N, class F>
__device__ __forceinline__ void static_for(F&& f) {
    sf_impl(f, std::make_integer_sequence<int, N>{});
}

// ---------------------------------------------------------------------------
// prep_pack: blocks 0..255 pack Wp2 into 32x32x16 B-frag layout
// ([kstep][ct][l]); 256..271 pack W1b (16x16x32 layout for Phase A);
// 272..279 fold k-consts (64 k each, 4-way e-split + LDS reduce);
// 280..283 fold A2/C2. All global reads coalesced.
// 32x32x16 B-frag: lane l holds B[k=kstep*16+(l>>5)*8+j][n=ct*32+(l&31)].
// 16x16x32 B-frag: lane l holds B[k=kb*32+(l>>4)*8+j][n=nt*16+(l&15)].
// ---------------------------------------------------------------------------
__global__ __launch_bounds__(256) void prep_pack_kernel(
    const float* __restrict__ Wsp,  const float* __restrict__ bsp,
    const float* __restrict__ Wp1,  const float* __restrict__ bp1,
    const float* __restrict__ gp1,  const float* __restrict__ btp1,
    const float* __restrict__ mp1,  const float* __restrict__ vp1,
    const float* __restrict__ Wp2,  const float* __restrict__ bp2,
    const float* __restrict__ gp2,  const float* __restrict__ btp2,
    const float* __restrict__ mp2,  const float* __restrict__ vp2,
    unsigned char* __restrict__ ws)
{
    __shared__ float tile[32 * 65];
    __shared__ float part[3][4][64];
    const int blk = blockIdx.x, t = threadIdx.x;

    if (blk < 272) {
        const float* src; int ncols, kb, ng;
        if (blk < 256) { kb = blk >> 4; ng = blk & 15; src = Wp2; ncols = 1024; }
        else { int b2 = blk - 256; kb = b2 >> 3; ng = b2 & 7; src = Wp1 + 64 * 512; ncols = 512; }
        const int k0 = kb * 32, n0 = ng * 64;
        #pragma unroll
        for (int it = 0; it < 2; ++it) {
            int c = t + it * 256;
            int r = c >> 4, c4 = c & 15;
            float4 v = *(const float4*)(src + (k0 + r) * ncols + n0 + c4 * 4);
            tile[r * 65 + c4 * 4 + 0] = v.x;
            tile[r * 65 + c4 * 4 + 1] = v.y;
            tile[r * 65 + c4 * 4 + 2] = v.z;
            tile[r * 65 + c4 * 4 + 3] = v.w;
        }
        __syncthreads();
        if (blk < 256) {
            const int l = t & 63, ch = (t >> 6) & 1, kh = t >> 7;
            const int nl = ch * 32 + (l & 31);
            const int kl = kh * 16 + ((l >> 5) & 1) * 8;
            uint4 o;
            o.x = pk_bf16(tile[(kl + 0) * 65 + nl], tile[(kl + 1) * 65 + nl]);
            o.y = pk_bf16(tile[(kl + 2) * 65 + nl], tile[(kl + 3) * 65 + nl]);
            o.z = pk_bf16(tile[(kl + 4) * 65 + nl], tile[(kl + 5) * 65 + nl]);
            o.w = pk_bf16(tile[(kl + 6) * 65 + nl], tile[(kl + 7) * 65 + nl]);
            const int kstep = kb * 2 + kh, ct = ng * 2 + ch;
            ((uint4*)(ws + BP2_OFF))[(kstep * 32 + ct) * 64 + l] = o;
        } else {
            int ntl = t >> 6, l = t & 63;
            int nl = ntl * 16 + (l & 15), kl = (l >> 4) * 8;
            uint4 o;
            o.x = pk_bf16(tile[(kl + 0) * 65 + nl], tile[(kl + 1) * 65 + nl]);
            o.y = pk_bf16(tile[(kl + 2) * 65 + nl], tile[(kl + 3) * 65 + nl]);
            o.z = pk_bf16(tile[(kl + 4) * 65 + nl], tile[(kl + 5) * 65 + nl]);
            o.w = pk_bf16(tile[(kl + 6) * 65 + nl], tile[(kl + 7) * 65 + nl]);
            ((uint4*)(ws + BP1_OFF))[((ng * 4 + ntl) * 2 + kb) * 64 + l] = o;
        }
    } else if (blk < 280) {
        const int kk = t & 63, eq = t >> 6;
        const int k = (blk - 272) * 64 + kk;
        float mx = 0.f, my = 0.f, cb = 0.f;
        #pragma unroll
        for (int e2 = 0; e2 < 16; ++e2) {
            int e = eq * 16 + e2;
            float wv = Wp1[e * 512 + k];
            mx = fmaf(Wsp[e],      wv, mx);
            my = fmaf(Wsp[64 + e], wv, my);
            cb = fmaf(bsp[e],      wv, cb);
        }
        part[0][eq][kk] = mx; part[1][eq][kk] = my; part[2][eq][kk] = cb;
        __syncthreads();
        if (t < 64) {
            const int k2 = (blk - 272) * 64 + t;
            float mxs = part[0][0][t] + part[0][1][t] + part[0][2][t] + part[0][3][t];
            float mys = part[1][0][t] + part[1][1][t] + part[1][2][t] + part[1][3][t];
            float cbs = part[2][0][t] + part[2][1][t] + part[2][2][t] + part[2][3][t];
            float a1 = gp1[k2] * rsqrtf(vp1[k2] + 1e-5f);
            ((float*)(ws + MX_OFF))[k2] = 0.05f * a1 * mxs;
            ((float*)(ws + MY_OFF))[k2] = 0.05f * a1 * mys;
            ((float*)(ws + CB_OFF))[k2] = 0.05f * a1 * cbs + (bp1[k2] - mp1[k2]) * a1 + btp1[k2];
            ((float*)(ws + SH_OFF))[k2] = 0.05f * a1;
        }
    } else {
        int n = (blk - 280) * 256 + t;
        float a = gp2[n] * rsqrtf(vp2[n] + 1e-5f);
        ((float*)(ws + A2_OFF))[n] = a;
        ((float*)(ws + C2_OFF))[n] = btp2[n] + (bp2[n] - mp2[n]) * a;
    }
}

// ---------------------------------------------------------------------------
// Phases A+B (both barriers included).
// ---------------------------------------------------------------------------
__device__ __forceinline__ void phaseAB(
    unsigned char* smem,
    const float* __restrict__ hst, const float* __restrict__ epos,
    const unsigned char* __restrict__ ws, int s, int ih, int tid)
{
    const int w    = tid >> 6;
    const int l    = tid & 63;
    const int quad = l >> 4;
    const int jl   = l & 15;

    // ---- Phase A: HH via MFMA (16x16x32) ----
    {
        union { unsigned u[4]; bf16x8 v; } afh[2];
        #pragma unroll
        for (int kb = 0; kb < 2; ++kb) {
            const float4* hp = (const float4*)(hst + (s * 16 + jl) * 64 + kb * 32 + quad * 8);
            float4 v0 = hp[0], v1 = hp[1];
            afh[kb].u[0] = pk_bf16(v0.x, v0.y);
            afh[kb].u[1] = pk_bf16(v0.z, v0.w);
            afh[kb].u[2] = pk_bf16(v1.x, v1.y);
            afh[kb].u[3] = pk_bf16(v1.z, v1.w);
        }
        const f32x4 fz = {0.f, 0.f, 0.f, 0.f};
        f32x4 acch[4] = {fz, fz, fz, fz};     // wave w -> k-cols w*64..+63
        #pragma unroll
        for (int kb = 0; kb < 2; ++kb) {
            #pragma unroll
            for (int ct = 0; ct < 4; ++ct) {
                bf16x8 bfr = *(const bf16x8*)(ws + BP1_OFF + ((((w * 4 + ct) * 2 + kb) * 64 + l) << 4));
                acch[ct] = __builtin_amdgcn_mfma_f32_16x16x32_bf16(afh[kb].v, bfr, acch[ct], 0, 0, 0);
            }
        }
        const float* SHg = (const float*)(ws + SH_OFF);
        const float* CBg = (const float*)(ws + CB_OFF);
        #pragma unroll
        for (int ct = 0; ct < 4; ++ct) {
            int col = (w * 4 + ct) * 16 + jl;        // k index
            float sh = SHg[col], cb = CBg[col];
            #pragma unroll
            for (int reg = 0; reg < 4; ++reg) {
                int j = quad * 4 + reg;
                float hv = fmaf(acch[ct][reg], sh, cb);
                *(unsigned short*)(smem + HH_LDS + j * 1024 + col * 2) = f2bf(hv);
            }
        }
    }
    __syncthreads();

    // ---- Phase B: construct Y1 (bf16, swizzled); chunk = kk*16+kc ----
    {
        const int i2 = tid >> 8;           // 0..1  (4 i each)
        const int j  = (tid >> 4) & 15;
        const int kc = tid & 15;
        float rx[4], ry[4];
        float pjx = epos[s * 32 + j * 2], pjy = epos[s * 32 + j * 2 + 1];
        #pragma unroll
        for (int ii = 0; ii < 4; ++ii) {
            int ig_ = ih * 8 + i2 * 4 + ii;
            rx[ii] = pjx - epos[s * 32 + ig_ * 2];
            ry[ii] = pjy - epos[s * 32 + ig_ * 2 + 1];
        }
        const f32x2 zero2 = {0.f, 0.f};
        #pragma unroll
        for (int kk = 0; kk < 4; ++kk) {
            int c16 = kk * 16 + kc;
            int k = c16 * 8;
            uint4 hh8 = *(const uint4*)(smem + HH_LDS + j * 1024 + k * 2);
            f32x4 mx0 = *(const f32x4*)(ws + MX_OFF + k * 4);
            f32x4 mx1 = *(const f32x4*)(ws + MX_OFF + k * 4 + 16);
            f32x4 my0 = *(const f32x4*)(ws + MY_OFF + k * 4);
            f32x4 my1 = *(const f32x4*)(ws + MY_OFF + k * 4 + 16);
            f32x2 mxp[4] = { {mx0[0],mx0[1]}, {mx0[2],mx0[3]}, {mx1[0],mx1[1]}, {mx1[2],mx1[3]} };
            f32x2 myp[4] = { {my0[0],my0[1]}, {my0[2],my0[3]}, {my1[0],my1[1]}, {my1[2],my1[3]} };
            f32x2 hhp[4];
            hhp[0][0] = bfbits2f(hh8.x << 16); hhp[0][1] = bfbits2f(hh8.x & 0xffff0000u);
            hhp[1][0] = bfbits2f(hh8.y << 16); hhp[1][1] = bfbits2f(hh8.y & 0xffff0000u);
            hhp[2][0] = bfbits2f(hh8.z << 16); hhp[2][1] = bfbits2f(hh8.z & 0xffff0000u);
            hhp[3][0] = bfbits2f(hh8.w << 16); hhp[3][1] = bfbits2f(hh8.w & 0xffff0000u);
            #pragma unroll
            for (int ii = 0; ii < 4; ++ii) {
                f32x2 rx2 = { rx[ii], rx[ii] };
                f32x2 ry2 = { ry[ii], ry[ii] };
                uint4 o;
                unsigned uu[4];
                #pragma unroll
                for (int p = 0; p < 4; ++p) {
                    f32x2 tt = __builtin_elementwise_fma(ry2, myp[p], hhp[p]);
                    tt = __builtin_elementwise_fma(rx2, mxp[p], tt);
                    tt = __builtin_elementwise_max(tt, zero2);
                    uu[p] = pk_bf16(tt[0], tt[1]);
                }
                o.x = uu[0]; o.y = uu[1]; o.z = uu[2]; o.w = uu[3];
                int r = (i2 * 4 + ii) * 16 + j;
                *(uint4*)(smem + Y1_LDS + y1off(r, c16)) = o;
            }
        }
    }
    __syncthreads();
}

// ---------------------------------------------------------------------------
// mm2 v17: WG = (scene s, i-half ih). 512 thr = 8 waves = 2 rowgroups x
// 4 colgroups. Wave = 2rt x 4ct, 2 passes. Static 64-step schedule,
// A ring-4 lead-2 (lgkmcnt 4), B ring-3 lead-2 (vmcnt 8), CACHED B loads
// (rowgroup pair shares B addresses -> L1 hits).
// ---------------------------------------------------------------------------
__global__ __launch_bounds__(512, 2) void mm2_kernel(
    const float* __restrict__ hst,
    const float* __restrict__ epos,
    const unsigned char* __restrict__ ws,
    float* __restrict__ out)
{
    __shared__ __align__(16) unsigned char smem[LDS_SZ];

    const int s   = blockIdx.x >> 1;     // 256 scenes
    const int ih  = blockIdx.x & 1;      // i-half
    const int tid = threadIdx.x;

    phaseAB(smem, hst, epos, ws, s, ih, tid);

    // ---- Phase C ----
    const int w = tid >> 6, l = tid & 63;
    const int lane31 = l & 31;           // A-frag m, C col
    const int hi = l >> 5;               // k-half; C row group
    const int sr = lane31 & 7;
    const int rg = w >> 2;               // rowgroup: rowtiles rg*2, rg*2+1
    const int cg = w & 3;                // colgroup: 4 coltiles per pass
    const float* A2 = (const float*)(ws + A2_OFF);
    const float* C2 = (const float*)(ws + C2_OFF);

    // A addr(rr, k) = ((av + (k>>2)*128) ^ ((k&3)<<5)) + rr*32768
    const int av = Y1_LDS + (rg * 64 + lane31) * 1024 + ((hi ^ sr) << 4);
    // B addr(pass, k, c) = bp + pass*16384 + k*32768 + c*1024
    const unsigned char* bp = ws + BP2_OFF + ((cg * 4) << 10) + (l << 4);

    const f32x16 fz16 = {0.f,0.f,0.f,0.f,0.f,0.f,0.f,0.f,
                         0.f,0.f,0.f,0.f,0.f,0.f,0.f,0.f};
    f32x16 acc[2][4];
    bf16x8 ar[4][2];   // A ring-of-4 (lead 2), slot = k&3
    bf16x8 br[3][4];   // B ring-of-3 (lead 2), slot = G%3

    #pragma unroll
    for (int rr = 0; rr < 2; ++rr)
        #pragma unroll
        for (int c = 0; c < 4; ++c) acc[rr][c] = fz16;

    // epilogue: bn2 + relu, maxpool over j, store fp32. 8 loads + 8 stores.
    // C/D 32x32: col = lane&31, row = (reg&3)+8*(reg>>2)+4*hi.
    auto epilogue = [&](int pass) {
        #pragma unroll
        for (int c = 0; c < 4; ++c) {
            const int col = (pass * 16 + cg * 4 + c) * 32 + lane31;
            const float a2 = A2[col], c2 = C2[col];
            #pragma unroll
            for (int rr = 0; rr < 2; ++rr) {
                float mv[2];
                #pragma unroll
                for (int hg = 0; hg < 2; ++hg) {
                    float v0 = fmaxf(fmaf(acc[rr][c][hg * 8 + 0], a2, c2), 0.f);
                    float v1 = fmaxf(fmaf(acc[rr][c][hg * 8 + 1], a2, c2), 0.f);
                    float v2 = fmaxf(fmaf(acc[rr][c][hg * 8 + 2], a2, c2), 0.f);
                    float v3 = fmaxf(fmaf(acc[rr][c][hg * 8 + 3], a2, c2), 0.f);
                    float v4 = fmaxf(fmaf(acc[rr][c][hg * 8 + 4], a2, c2), 0.f);
                    float v5 = fmaxf(fmaf(acc[rr][c][hg * 8 + 5], a2, c2), 0.f);
                    float v6 = fmaxf(fmaf(acc[rr][c][hg * 8 + 6], a2, c2), 0.f);
                    float v7 = fmaxf(fmaf(acc[rr][c][hg * 8 + 7], a2, c2), 0.f);
                    float m = fmaxf(fmaxf(fmaxf(v0, v1), fmaxf(v2, v3)),
                                    fmaxf(fmaxf(v4, v5), fmaxf(v6, v7)));
                    mv[hg] = fmaxf(m, __shfl_xor(m, 32, 64));
                }
                const int iloc = (rg * 2 + rr) * 2 + hi;
                const float vout = hi ? mv[1] : mv[0];
                const int orow = s * 16 + ih * 8 + iloc;
                __builtin_nontemporal_store(vout, &out[orow * 1024 + col]);
            }
        }
    };

    // one step of the global 64-step schedule (G = pass*32 + k)
    auto stepG = [&](auto Gc) {
        constexpr int G  = decltype(Gc)::value;
        constexpr int GN = G + 2;                   // issue distance 2
        if constexpr (GN <= 63) {
            constexpr int pn = GN >> 5, kn = GN & 31;
            constexpr int bs = GN % 3, as = GN & 3;
            const unsigned char* b = bp + (pn * 16384 + kn * 32768);
            #pragma unroll
            for (int c = 0; c < 4; ++c)
                br[bs][c] = *(const bf16x8*)(b + c * 1024);   // cached (L1 shared by rg pair)
            constexpr int add = (kn >> 2) * 128;
            constexpr int xr  = (kn & 3) << 5;
            ar[as][0] = *(const bf16x8*)(smem + ((av + add) ^ xr));
            ar[as][1] = *(const bf16x8*)(smem + (((av + add) ^ xr) + 32768));
        }
        // waits (in-order vmcnt retire):
        //   steady: B lead-2 -> vmcnt(8); A lead-2 -> lgkmcnt(4).
        //   G=32/33: 16 epilogue vm ops (8 a2c2 loads + 8 stores) precede
        //   B(34)/B(35) in issue order -> vmcnt(16) covers B(32)/B(33);
        //   from G=34 steady vmcnt(8) retires the remaining epi ops + B(34).
        if constexpr (G == 32 || G == 33)
            asm volatile("s_waitcnt vmcnt(16) lgkmcnt(4)" ::: "memory");
        else if constexpr (G == 62)
            asm volatile("s_waitcnt vmcnt(4) lgkmcnt(2)" ::: "memory");
        else if constexpr (G == 63)
            asm volatile("s_waitcnt vmcnt(0) lgkmcnt(0)" ::: "memory");
        else
            asm volatile("s_waitcnt vmcnt(8) lgkmcnt(4)" ::: "memory");
        __builtin_amdgcn_sched_barrier(0);
        constexpr int as2 = G & 3, bs2 = G % 3;
        #pragma unroll
        for (int c = 0; c < 4; ++c)
            #pragma unroll
            for (int rr = 0; rr < 2; ++rr)
                acc[rr][c] = __builtin_amdgcn_mfma_f32_32x32x16_bf16(
                    ar[as2][rr], br[bs2][c], acc[rr][c], 0, 0, 0);
    };

    // prologue: B(0),B(1) (8 loads); A(0),A(1) (4 ds_reads)
    #pragma unroll
    for (int g = 0; g < 2; ++g)
        #pragma unroll
        for (int c = 0; c < 4; ++c)
            br[g][c] = *(const bf16x8*)(bp + g * 32768 + c * 1024);
    ar[0][0] = *(const bf16x8*)(smem + av);
    ar[0][1] = *(const bf16x8*)(smem + av + 32768);
    ar[1][0] = *(const bf16x8*)(smem + (av ^ 32));
    ar[1][1] = *(const bf16x8*)(smem + ((av ^ 32) + 32768));

    static_for<32>(stepG);                          // G = 0..31 (pass 0)
    __builtin_amdgcn_sched_barrier(0);
    epilogue(0);
    #pragma unroll
    for (int rr = 0; rr < 2; ++rr)
        #pragma unroll
        for (int c = 0; c < 4; ++c) acc[rr][c] = fz16;
    __builtin_amdgcn_sched_barrier(0);
    static_for<32>([&](auto kc) {                   // G = 32..63 (pass 1)
        stepG(std::integral_constant<int, decltype(kc)::value + 32>{});
    });
    __builtin_amdgcn_sched_barrier(0);
    epilogue(1);
}

extern "C" void kernel_launch(void* const* d_in, const int* in_sizes, int n_in,
                              void* d_out, int out_size, void* d_ws, size_t ws_size,
                              hipStream_t stream) {
    const float* hst  = (const float*)d_in[0];
    const float* epos = (const float*)d_in[1];
    const float* Wsp  = (const float*)d_in[4];
    const float* bsp  = (const float*)d_in[5];
    const float* Wp1  = (const float*)d_in[20];
    const float* bp1  = (const float*)d_in[21];
    const float* gp1  = (const float*)d_in[22];
    const float* btp1 = (const float*)d_in[23];
    const float* mp1  = (const float*)d_in[24];
    const float* vp1  = (const float*)d_in[25];
    const float* Wp2  = (const float*)d_in[26];
    const float* bp2  = (const float*)d_in[27];
    const float* gp2  = (const float*)d_in[28];
    const float* btp2 = (const float*)d_in[29];
    const float* mp2  = (const float*)d_in[30];
    const float* vp2  = (const float*)d_in[31];
    unsigned char* ws = (unsigned char*)d_ws;
    float* out = (float*)d_out;

    // 256 (Wp2 pack) + 16 (W1b pack) + 8 (k-consts) + 4 (A2/C2) = 284 blocks
    prep_pack_kernel<<<284, 256, 0, stream>>>(Wsp, bsp, Wp1, bp1, gp1, btp1, mp1, vp1,
                                              Wp2, bp2, gp2, btp2, mp2, vp2, ws);
    // 256 scenes x 2 i-halves, 512 threads (8 waves)
    mm2_kernel<<<512, 512, 0, stream>>>(hst, epos, ws, out);
}